// Round 11
// baseline (658.751 us; speedup 1.0000x reference)
//
#include <hip/hip_runtime.h>
#include <hip/hip_fp16.h>

#define I_DIM 1152
#define B_DIM 64
#define J_DIM 64
#define D_DIM 32
#define K_DIM 64
#define JD    2048   // J*D
#define ICHUNK 16
#define NCHUNK 72    // I_DIM / ICHUNK

typedef _Float16 half8 __attribute__((ext_vector_type(8)));
typedef _Float16 half4 __attribute__((ext_vector_type(4)));
typedef float f32x4 __attribute__((ext_vector_type(4)));
typedef unsigned int u32x4 __attribute__((ext_vector_type(4)));

// split two f32x4 (8 consecutive f32) into fp16 hi + lo residual
__device__ inline void split8(const f32x4 a, const f32x4 b, half8& hi, half8& lo) {
  const float f[8] = {a.x, a.y, a.z, a.w, b.x, b.y, b.z, b.w};
  #pragma unroll
  for (int e = 0; e < 8; ++e) {
    _Float16 h = (_Float16)f[e];
    hi[e] = h;
    lo[e] = (_Float16)(f[e] - (float)h);
  }
}

// -----------------------------------------------------------------------------
// K1 (MFMA): u_hat[i][b][jd] fp16 = sum_k W[i][jd][k] * x[b][i][k]
// u = wh*xh + wh*xl + wl*xh (split-fp16, ~2^-21 rel err).
// A = W (M=jd), B = x (N=b); D: row=(lane>>4)*4+r = jd, col=lane&15 = b.
// ROUND-6 CONFIG (best measured: k1~236us): 256-thr block-per-i, plain loads
// (L3 serves ~260MB of W; nt loads +370MB HBM, r8), plain LDS-burst stores
// (nt stores +200MB RMW fetches, r9; 2-wave blocks thrash L3, r10).
// NEW: burst moved AFTER the group's last prefetch load, so the 8 stores are
// the youngest VMEM ops -- next group's W-data vmcnt wait never drains them.
// -----------------------------------------------------------------------------
__global__ __launch_bounds__(256, 4) void k1_uhat(
    const float* __restrict__ x, const float* __restrict__ W,
    __half* __restrict__ uhat) {
  __shared__ __half tile[4 * 64 * 64];     // 4 waves x 8KB, wave-private
  const int i = blockIdx.x;                // 0..1151
  const int lane = threadIdx.x & 63;
  const int wave = threadIdx.x >> 6;
  const int kof = (lane >> 4) * 8;         // k sub-offset (frag layout)
  char* my = (char*)(tile + wave * 64 * 64);

  // ---- x fragments (B-operand: col b = m*16 + (lane&15)), split once ----
  half8 xh0[4], xh1[4], xl0[4], xl1[4];
  #pragma unroll
  for (int m = 0; m < 4; ++m) {
    const float* xr = x + ((size_t)(m * 16 + (lane & 15)) * I_DIM + i) * K_DIM + kof;
    split8(*(const f32x4*)xr,        *(const f32x4*)(xr + 4),  xh0[m], xl0[m]);
    split8(*(const f32x4*)(xr + 32), *(const f32x4*)(xr + 36), xh1[m], xl1[m]);
  }

  f32x4 w0[4], w1[4], w2[4], w3[4];
  auto loadW = [&](int cg, f32x4* dst) {
    const int row = wave * 512 + cg * 16 + (lane & 15);     // jd row (A-operand)
    const float* p = W + ((size_t)i * JD + row) * K_DIM + kof;
    dst[0] = *(const f32x4*)p;
    dst[1] = *(const f32x4*)(p + 4);
    dst[2] = *(const f32x4*)(p + 32);
    dst[3] = *(const f32x4*)(p + 36);
  };

  // mfma + swizzled ds_write for one col-group (no global stores here)
  auto process = [&](int cg, const f32x4* wc) {
    half8 wh0, wl0, wh1, wl1;
    split8(wc[0], wc[1], wh0, wl0);
    split8(wc[2], wc[3], wh1, wl1);
    const int g = lane >> 4;
    const int c = (cg & 3) * 4 + g;        // logical 8B chunk (jd_local/4)
    #pragma unroll
    for (int m = 0; m < 4; ++m) {
      f32x4 acc = {0.f, 0.f, 0.f, 0.f};
      acc = __builtin_amdgcn_mfma_f32_16x16x32_f16(wh0, xh0[m], acc, 0, 0, 0);
      acc = __builtin_amdgcn_mfma_f32_16x16x32_f16(wh1, xh1[m], acc, 0, 0, 0);
      acc = __builtin_amdgcn_mfma_f32_16x16x32_f16(wh0, xl0[m], acc, 0, 0, 0);
      acc = __builtin_amdgcn_mfma_f32_16x16x32_f16(wh1, xl1[m], acc, 0, 0, 0);
      acc = __builtin_amdgcn_mfma_f32_16x16x32_f16(wl0, xh0[m], acc, 0, 0, 0);
      acc = __builtin_amdgcn_mfma_f32_16x16x32_f16(wl1, xh1[m], acc, 0, 0, 0);
      const int b = m * 16 + (lane & 15);
      half4 o;
      #pragma unroll
      for (int r = 0; r < 4; ++r) o[r] = (_Float16)acc[r];
      // swizzled ds_write: row b (128B), phys chunk = c ^ ((b&7)<<1)
      *(half4*)(my + b * 128 + ((c ^ ((b & 7) << 1)) * 8)) = o;
    }
  };

  // burst the wave's 8KB tile -> global: 8 instrs x (8 rows x 128B dense)
  auto burst = [&](int cg0) {
    const int jd0 = wave * 512 + cg0 * 16;       // tile's first jd
    #pragma unroll
    for (int t = 0; t < 8; ++t) {
      const int b = t * 8 + (lane >> 3);
      const int c2 = (lane & 7) * 2;             // even chunk -> 16B aligned
      const u32x4 v = *(const u32x4*)(my + b * 128 + ((c2 ^ ((b & 7) << 1)) * 8));
      *(u32x4*)((char*)(uhat + ((size_t)i * B_DIM + b) * JD + jd0) + (lane & 7) * 16) = v;
    }
  };

  loadW(0, w0); loadW(1, w1); loadW(2, w2); loadW(3, w3);
  #pragma unroll 1
  for (int cg = 0; cg < 32; cg += 4) {
    process(cg + 0, w0); if (cg + 4 < 32) loadW(cg + 4, w0);
    process(cg + 1, w1); if (cg + 5 < 32) loadW(cg + 5, w1);
    process(cg + 2, w2); if (cg + 6 < 32) loadW(cg + 6, w2);
    process(cg + 3, w3); if (cg + 7 < 32) loadW(cg + 7, w3);
    burst(cg);   // stores issued AFTER all this group's prefetch loads
  }
}

// -----------------------------------------------------------------------------
// K3: s0 = (1/J) * sum_i u_hat -> squash -> v0.  u_hat layout [i][b][jd].
// -----------------------------------------------------------------------------
__global__ __launch_bounds__(256) void k3_s0(
    const __half* __restrict__ uhat, float* __restrict__ v0) {
  const int b = blockIdx.y;
  const int jd = blockIdx.x * 512 + threadIdx.x * 2;
  const __half* p = uhat + (size_t)b * JD + jd;
  float s0 = 0.f, s1 = 0.f;
  #pragma unroll 16
  for (int i = 0; i < I_DIM; ++i) {
    const __half2 h = *(const __half2*)(p + (size_t)i * B_DIM * JD);
    s0 += __low2float(h);
    s1 += __high2float(h);
  }
  s0 *= (1.f / 64.f);
  s1 *= (1.f / 64.f);
  float n2 = s0 * s0 + s1 * s1;
  #pragma unroll
  for (int w = 1; w < 16; w <<= 1) n2 += __shfl_xor(n2, w);
  const float sc = n2 / (1.f + n2) * rsqrtf(n2 + 1e-9f);
  float* o = v0 + (size_t)b * JD + jd;
  o[0] = s0 * sc;
  o[1] = s1 * sc;
}

// -----------------------------------------------------------------------------
// K4: one routing pass. u_hat row for (b,i) = uhat[(i*B + b)*JD], contiguous 4KB.
// -----------------------------------------------------------------------------
__global__ __launch_bounds__(64) void k4_route(
    const __half* __restrict__ uhat, const float* __restrict__ v,
    float* __restrict__ spart) {
  const int chunk = blockIdx.x;   // 0..NCHUNK-1
  const int b = blockIdx.y;       // 0..63
  const int lane = threadIdx.x;   // 0..63
  const int jq = lane >> 2;       // 0..15
  const int d0 = (lane & 3) * 8;

  float vr[4][8];
  #pragma unroll
  for (int q = 0; q < 4; ++q) {
    const float* vp = v + ((size_t)b * J_DIM + q * 16 + jq) * D_DIM + d0;
    f32x4 a0 = *(const f32x4*)vp;
    f32x4 a1 = *(const f32x4*)(vp + 4);
    vr[q][0] = a0.x; vr[q][1] = a0.y; vr[q][2] = a0.z; vr[q][3] = a0.w;
    vr[q][4] = a1.x; vr[q][5] = a1.y; vr[q][6] = a1.z; vr[q][7] = a1.w;
  }
  float sacc[4][8];
  #pragma unroll
  for (int q = 0; q < 4; ++q)
    #pragma unroll
    for (int cc = 0; cc < 8; ++cc) sacc[q][cc] = 0.f;

  for (int ii = 0; ii < ICHUNK; ++ii) {
    const int i = chunk * ICHUNK + ii;
    const __half* row = uhat + ((size_t)i * B_DIM + b) * JD;
    float ur[4][8];
    float a[4];
    #pragma unroll
    for (int q = 0; q < 4; ++q) {
      u32x4 raw = *(const u32x4*)&row[q * 512 + lane * 8];
      const __half* hp = (const __half*)&raw;
      float p = 0.f;
      #pragma unroll
      for (int cc = 0; cc < 8; ++cc) {
        ur[q][cc] = __half2float(hp[cc]);
        p = fmaf(ur[q][cc], vr[q][cc], p);
      }
      p += __shfl_xor(p, 1);
      p += __shfl_xor(p, 2);
      a[q] = p;  // a[b, j=q*16+jq], replicated over the quad
    }
    float m = fmaxf(fmaxf(a[0], a[1]), fmaxf(a[2], a[3]));
    #pragma unroll
    for (int w = 4; w < 64; w <<= 1) m = fmaxf(m, __shfl_xor(m, w));
    float e[4]; float es = 0.f;
    #pragma unroll
    for (int q = 0; q < 4; ++q) { e[q] = __expf(a[q] - m); es += e[q]; }
    #pragma unroll
    for (int w = 4; w < 64; w <<= 1) es += __shfl_xor(es, w);
    const float inv = 4.f / es;  // each j counted 4x in the wave sum
    #pragma unroll
    for (int q = 0; q < 4; ++q) {
      const float cj = e[q] * inv;
      #pragma unroll
      for (int cc = 0; cc < 8; ++cc)
        sacc[q][cc] = fmaf(cj, ur[q][cc], sacc[q][cc]);
    }
  }
  float* sp = spart + ((size_t)(b * NCHUNK + chunk)) * JD;
  #pragma unroll
  for (int q = 0; q < 4; ++q) {
    float* o = sp + (q * 16 + jq) * D_DIM + d0;
    *(f32x4*)o       = f32x4{sacc[q][0], sacc[q][1], sacc[q][2], sacc[q][3]};
    *(f32x4*)(o + 4) = f32x4{sacc[q][4], sacc[q][5], sacc[q][6], sacc[q][7]};
  }
}

// -----------------------------------------------------------------------------
// K5: reduce s-partials over chunks -> squash -> vout (+optional vprev sum).
// -----------------------------------------------------------------------------
__global__ __launch_bounds__(256) void k5_reduce(
    const float* __restrict__ spart, const float* __restrict__ vprev,
    float* __restrict__ vout, float* __restrict__ vsum) {
  const int b = blockIdx.y;
  const int jd = blockIdx.x * 256 + threadIdx.x;
  const float* p = spart + (size_t)b * NCHUNK * JD + jd;
  float s = 0.f;
  #pragma unroll 8
  for (int ch = 0; ch < NCHUNK; ++ch) s += p[(size_t)ch * JD];
  float n2 = s * s;
  #pragma unroll
  for (int w = 1; w < 32; w <<= 1) n2 += __shfl_xor(n2, w);
  const float sc = n2 / (1.f + n2) * rsqrtf(n2 + 1e-9f);
  const float vv = s * sc;
  vout[(size_t)b * JD + jd] = vv;
  if (vsum) vsum[(size_t)b * JD + jd] = vv + vprev[(size_t)b * JD + jd];
}

extern "C" void kernel_launch(void* const* d_in, const int* in_sizes, int n_in,
                              void* d_out, int out_size, void* d_ws, size_t ws_size,
                              hipStream_t stream) {
  const float* x = (const float*)d_in[0];   // (B, I, 1, K, 1) f32
  const float* W = (const float*)d_in[1];   // (1, I, J, D, K) f32
  float* out = (float*)d_out;               // (B, J, 1, D, 1) f32

  char* ws = (char*)d_ws;
  __half* uhat = (__half*)ws;                                   // 302 MB, [i][b][jd]
  size_t off = (size_t)B_DIM * I_DIM * JD * sizeof(__half);
  float* spart = (float*)(ws + off);                            // 37.75 MB
  off += (size_t)B_DIM * NCHUNK * JD * sizeof(float);
  float* v0 = (float*)(ws + off);   off += (size_t)B_DIM * JD * sizeof(float);
  float* v1 = (float*)(ws + off);   off += (size_t)B_DIM * JD * sizeof(float);
  float* vsum = (float*)(ws + off);

  // u_hat via split-fp16 MFMA; LDS-staged dense burst stores (round-6 config,
  // burst reordered after prefetch loads)
  k1_uhat<<<I_DIM, 256, 0, stream>>>(x, W, uhat);
  // it 0: s0 = mean_i u_hat -> v0
  k3_s0<<<dim3(4, B_DIM), 256, 0, stream>>>(uhat, v0);
  // it 1: b1 = u.v0 -> softmax -> s1 -> v1 (and vsum = v0+v1)
  k4_route<<<dim3(NCHUNK, B_DIM), 64, 0, stream>>>(uhat, v0, spart);
  k5_reduce<<<dim3(8, B_DIM), 256, 0, stream>>>(spart, v0, v1, vsum);
  // it 2: b2 = u.(v0+v1) -> softmax -> s2 -> v2 = output
  k4_route<<<dim3(NCHUNK, B_DIM), 64, 0, stream>>>(uhat, vsum, spart);
  k5_reduce<<<dim3(8, B_DIM), 256, 0, stream>>>(spart, nullptr, out, nullptr);
}

// Round 12
// 656.755 us; speedup vs baseline: 1.0030x; 1.0030x over previous
//
#include <hip/hip_runtime.h>
#include <hip/hip_fp16.h>

#define I_DIM 1152
#define B_DIM 64
#define J_DIM 64
#define D_DIM 32
#define K_DIM 64
#define JD    2048   // J*D
#define ICHUNK 16
#define NCHUNK 72    // I_DIM / ICHUNK

typedef _Float16 half8 __attribute__((ext_vector_type(8)));
typedef _Float16 half4 __attribute__((ext_vector_type(4)));
typedef float f32x4 __attribute__((ext_vector_type(4)));
typedef unsigned int u32x4 __attribute__((ext_vector_type(4)));

// split two f32x4 (8 consecutive f32) into fp16 hi + lo residual
__device__ inline void split8(const f32x4 a, const f32x4 b, half8& hi, half8& lo) {
  const float f[8] = {a.x, a.y, a.z, a.w, b.x, b.y, b.z, b.w};
  #pragma unroll
  for (int e = 0; e < 8; ++e) {
    _Float16 h = (_Float16)f[e];
    hi[e] = h;
    lo[e] = (_Float16)(f[e] - (float)h);
  }
}

// -----------------------------------------------------------------------------
// K1 (MFMA): u_hat[i][b][jd] fp16 = sum_k W[i][jd][k] * x[b][i][k]
// u = wh*xh + wh*xl + wl*xh (split-fp16, ~2^-21 rel err).
// A = W (M=jd), B = x (N=b); D: row=(lane>>4)*4+r = jd, col=lane&15 = b.
// EXACT ROUND-6 CONFIG -- best measured (total 406us, k1 ~240us).
// Measured refutations of every deviation: nt loads +370MB HBM (r8);
// nt stores +200MB RMW fetches (r9); 2-wave blocks thrash L3, FETCH 1.17GB
// (r10); burst-after-prefetch reorder serializes store drain, k1 477us (r11).
// Store path: per-wave 8KB LDS tile, XOR-swizzled, burst as 8x1KB dense
// INSIDE process() at (cg&3)==3, i.e. before the group's last prefetch load.
// -----------------------------------------------------------------------------
__global__ __launch_bounds__(256, 4) void k1_uhat(
    const float* __restrict__ x, const float* __restrict__ W,
    __half* __restrict__ uhat) {
  __shared__ __half tile[4 * 64 * 64];     // 4 waves x 8KB, wave-private
  const int i = blockIdx.x;                // 0..1151
  const int lane = threadIdx.x & 63;
  const int wave = threadIdx.x >> 6;
  const int kof = (lane >> 4) * 8;         // k sub-offset (frag layout)
  char* my = (char*)(tile + wave * 64 * 64);

  // ---- x fragments (B-operand: col b = m*16 + (lane&15)), split once ----
  half8 xh0[4], xh1[4], xl0[4], xl1[4];
  #pragma unroll
  for (int m = 0; m < 4; ++m) {
    const float* xr = x + ((size_t)(m * 16 + (lane & 15)) * I_DIM + i) * K_DIM + kof;
    split8(*(const f32x4*)xr,        *(const f32x4*)(xr + 4),  xh0[m], xl0[m]);
    split8(*(const f32x4*)(xr + 32), *(const f32x4*)(xr + 36), xh1[m], xl1[m]);
  }

  f32x4 w0[4], w1[4], w2[4], w3[4];
  auto loadW = [&](int cg, f32x4* dst) {
    const int row = wave * 512 + cg * 16 + (lane & 15);     // jd row (A-operand)
    const float* p = W + ((size_t)i * JD + row) * K_DIM + kof;
    dst[0] = *(const f32x4*)p;
    dst[1] = *(const f32x4*)(p + 4);
    dst[2] = *(const f32x4*)(p + 32);
    dst[3] = *(const f32x4*)(p + 36);
  };

  auto process = [&](int cg, const f32x4* wc) {
    half8 wh0, wl0, wh1, wl1;
    split8(wc[0], wc[1], wh0, wl0);
    split8(wc[2], wc[3], wh1, wl1);
    const int g = lane >> 4;
    const int c = (cg & 3) * 4 + g;        // logical 8B chunk (jd_local/4)
    #pragma unroll
    for (int m = 0; m < 4; ++m) {
      f32x4 acc = {0.f, 0.f, 0.f, 0.f};
      acc = __builtin_amdgcn_mfma_f32_16x16x32_f16(wh0, xh0[m], acc, 0, 0, 0);
      acc = __builtin_amdgcn_mfma_f32_16x16x32_f16(wh1, xh1[m], acc, 0, 0, 0);
      acc = __builtin_amdgcn_mfma_f32_16x16x32_f16(wh0, xl0[m], acc, 0, 0, 0);
      acc = __builtin_amdgcn_mfma_f32_16x16x32_f16(wh1, xl1[m], acc, 0, 0, 0);
      acc = __builtin_amdgcn_mfma_f32_16x16x32_f16(wl0, xh0[m], acc, 0, 0, 0);
      acc = __builtin_amdgcn_mfma_f32_16x16x32_f16(wl1, xh1[m], acc, 0, 0, 0);
      const int b = m * 16 + (lane & 15);
      half4 o;
      #pragma unroll
      for (int r = 0; r < 4; ++r) o[r] = (_Float16)acc[r];
      // swizzled ds_write: row b (128B), phys chunk = c ^ ((b&7)<<1)
      *(half4*)(my + b * 128 + ((c ^ ((b & 7) << 1)) * 8)) = o;
    }
    if ((cg & 3) == 3) {
      // burst 8KB tile -> global: 8 instrs x (8 rows x 128B dense)
      const int jd0 = wave * 512 + (cg & ~3) * 16;   // tile's first jd
      #pragma unroll
      for (int t = 0; t < 8; ++t) {
        const int b = t * 8 + (lane >> 3);
        const int c2 = (lane & 7) * 2;               // even chunk -> 16B aligned
        const u32x4 v = *(const u32x4*)(my + b * 128 + ((c2 ^ ((b & 7) << 1)) * 8));
        *(u32x4*)((char*)(uhat + ((size_t)i * B_DIM + b) * JD + jd0) + (lane & 7) * 16) = v;
      }
    }
  };

  loadW(0, w0); loadW(1, w1); loadW(2, w2); loadW(3, w3);
  #pragma unroll 1
  for (int cg = 0; cg < 32; cg += 4) {
    process(cg + 0, w0); if (cg + 4 < 32) loadW(cg + 4, w0);
    process(cg + 1, w1); if (cg + 5 < 32) loadW(cg + 5, w1);
    process(cg + 2, w2); if (cg + 6 < 32) loadW(cg + 6, w2);
    process(cg + 3, w3); if (cg + 7 < 32) loadW(cg + 7, w3);
  }
}

// -----------------------------------------------------------------------------
// K3: s0 = (1/J) * sum_i u_hat -> squash -> v0.  u_hat layout [i][b][jd].
// -----------------------------------------------------------------------------
__global__ __launch_bounds__(256) void k3_s0(
    const __half* __restrict__ uhat, float* __restrict__ v0) {
  const int b = blockIdx.y;
  const int jd = blockIdx.x * 512 + threadIdx.x * 2;
  const __half* p = uhat + (size_t)b * JD + jd;
  float s0 = 0.f, s1 = 0.f;
  #pragma unroll 16
  for (int i = 0; i < I_DIM; ++i) {
    const __half2 h = *(const __half2*)(p + (size_t)i * B_DIM * JD);
    s0 += __low2float(h);
    s1 += __high2float(h);
  }
  s0 *= (1.f / 64.f);
  s1 *= (1.f / 64.f);
  float n2 = s0 * s0 + s1 * s1;
  #pragma unroll
  for (int w = 1; w < 16; w <<= 1) n2 += __shfl_xor(n2, w);
  const float sc = n2 / (1.f + n2) * rsqrtf(n2 + 1e-9f);
  float* o = v0 + (size_t)b * JD + jd;
  o[0] = s0 * sc;
  o[1] = s1 * sc;
}

// -----------------------------------------------------------------------------
// K4: one routing pass. u_hat row for (b,i) = uhat[(i*B + b)*JD], contiguous 4KB.
// -----------------------------------------------------------------------------
__global__ __launch_bounds__(64) void k4_route(
    const __half* __restrict__ uhat, const float* __restrict__ v,
    float* __restrict__ spart) {
  const int chunk = blockIdx.x;   // 0..NCHUNK-1
  const int b = blockIdx.y;       // 0..63
  const int lane = threadIdx.x;   // 0..63
  const int jq = lane >> 2;       // 0..15
  const int d0 = (lane & 3) * 8;

  float vr[4][8];
  #pragma unroll
  for (int q = 0; q < 4; ++q) {
    const float* vp = v + ((size_t)b * J_DIM + q * 16 + jq) * D_DIM + d0;
    f32x4 a0 = *(const f32x4*)vp;
    f32x4 a1 = *(const f32x4*)(vp + 4);
    vr[q][0] = a0.x; vr[q][1] = a0.y; vr[q][2] = a0.z; vr[q][3] = a0.w;
    vr[q][4] = a1.x; vr[q][5] = a1.y; vr[q][6] = a1.z; vr[q][7] = a1.w;
  }
  float sacc[4][8];
  #pragma unroll
  for (int q = 0; q < 4; ++q)
    #pragma unroll
    for (int cc = 0; cc < 8; ++cc) sacc[q][cc] = 0.f;

  for (int ii = 0; ii < ICHUNK; ++ii) {
    const int i = chunk * ICHUNK + ii;
    const __half* row = uhat + ((size_t)i * B_DIM + b) * JD;
    float ur[4][8];
    float a[4];
    #pragma unroll
    for (int q = 0; q < 4; ++q) {
      u32x4 raw = *(const u32x4*)&row[q * 512 + lane * 8];
      const __half* hp = (const __half*)&raw;
      float p = 0.f;
      #pragma unroll
      for (int cc = 0; cc < 8; ++cc) {
        ur[q][cc] = __half2float(hp[cc]);
        p = fmaf(ur[q][cc], vr[q][cc], p);
      }
      p += __shfl_xor(p, 1);
      p += __shfl_xor(p, 2);
      a[q] = p;  // a[b, j=q*16+jq], replicated over the quad
    }
    float m = fmaxf(fmaxf(a[0], a[1]), fmaxf(a[2], a[3]));
    #pragma unroll
    for (int w = 4; w < 64; w <<= 1) m = fmaxf(m, __shfl_xor(m, w));
    float e[4]; float es = 0.f;
    #pragma unroll
    for (int q = 0; q < 4; ++q) { e[q] = __expf(a[q] - m); es += e[q]; }
    #pragma unroll
    for (int w = 4; w < 64; w <<= 1) es += __shfl_xor(es, w);
    const float inv = 4.f / es;  // each j counted 4x in the wave sum
    #pragma unroll
    for (int q = 0; q < 4; ++q) {
      const float cj = e[q] * inv;
      #pragma unroll
      for (int cc = 0; cc < 8; ++cc)
        sacc[q][cc] = fmaf(cj, ur[q][cc], sacc[q][cc]);
    }
  }
  float* sp = spart + ((size_t)(b * NCHUNK + chunk)) * JD;
  #pragma unroll
  for (int q = 0; q < 4; ++q) {
    float* o = sp + (q * 16 + jq) * D_DIM + d0;
    *(f32x4*)o       = f32x4{sacc[q][0], sacc[q][1], sacc[q][2], sacc[q][3]};
    *(f32x4*)(o + 4) = f32x4{sacc[q][4], sacc[q][5], sacc[q][6], sacc[q][7]};
  }
}

// -----------------------------------------------------------------------------
// K5: reduce s-partials over chunks -> squash -> vout (+optional vprev sum).
// -----------------------------------------------------------------------------
__global__ __launch_bounds__(256) void k5_reduce(
    const float* __restrict__ spart, const float* __restrict__ vprev,
    float* __restrict__ vout, float* __restrict__ vsum) {
  const int b = blockIdx.y;
  const int jd = blockIdx.x * 256 + threadIdx.x;
  const float* p = spart + (size_t)b * NCHUNK * JD + jd;
  float s = 0.f;
  #pragma unroll 8
  for (int ch = 0; ch < NCHUNK; ++ch) s += p[(size_t)ch * JD];
  float n2 = s * s;
  #pragma unroll
  for (int w = 1; w < 32; w <<= 1) n2 += __shfl_xor(n2, w);
  const float sc = n2 / (1.f + n2) * rsqrtf(n2 + 1e-9f);
  const float vv = s * sc;
  vout[(size_t)b * JD + jd] = vv;
  if (vsum) vsum[(size_t)b * JD + jd] = vv + vprev[(size_t)b * JD + jd];
}

extern "C" void kernel_launch(void* const* d_in, const int* in_sizes, int n_in,
                              void* d_out, int out_size, void* d_ws, size_t ws_size,
                              hipStream_t stream) {
  const float* x = (const float*)d_in[0];   // (B, I, 1, K, 1) f32
  const float* W = (const float*)d_in[1];   // (1, I, J, D, K) f32
  float* out = (float*)d_out;               // (B, J, 1, D, 1) f32

  char* ws = (char*)d_ws;
  __half* uhat = (__half*)ws;                                   // 302 MB, [i][b][jd]
  size_t off = (size_t)B_DIM * I_DIM * JD * sizeof(__half);
  float* spart = (float*)(ws + off);                            // 37.75 MB
  off += (size_t)B_DIM * NCHUNK * JD * sizeof(float);
  float* v0 = (float*)(ws + off);   off += (size_t)B_DIM * JD * sizeof(float);
  float* v1 = (float*)(ws + off);   off += (size_t)B_DIM * JD * sizeof(float);
  float* vsum = (float*)(ws + off);

  // u_hat via split-fp16 MFMA; LDS-staged dense burst stores (round-6 exact)
  k1_uhat<<<I_DIM, 256, 0, stream>>>(x, W, uhat);
  // it 0: s0 = mean_i u_hat -> v0
  k3_s0<<<dim3(4, B_DIM), 256, 0, stream>>>(uhat, v0);
  // it 1: b1 = u.v0 -> softmax -> s1 -> v1 (and vsum = v0+v1)
  k4_route<<<dim3(NCHUNK, B_DIM), 64, 0, stream>>>(uhat, v0, spart);
  k5_reduce<<<dim3(8, B_DIM), 256, 0, stream>>>(spart, v0, v1, vsum);
  // it 2: b2 = u.(v0+v1) -> softmax -> s2 -> v2 = output
  k4_route<<<dim3(NCHUNK, B_DIM), 64, 0, stream>>>(uhat, vsum, spart);
  k5_reduce<<<dim3(8, B_DIM), 256, 0, stream>>>(spart, nullptr, out, nullptr);
}

// Round 13
// 408.839 us; speedup vs baseline: 1.6113x; 1.6064x over previous
//
#include <hip/hip_runtime.h>
#include <hip/hip_fp16.h>

#define I_DIM 1152
#define B_DIM 64
#define J_DIM 64
#define D_DIM 32
#define K_DIM 64
#define JD    2048   // J*D
#define ICHUNK 16
#define NCHUNK 72    // I_DIM / ICHUNK

typedef _Float16 half8 __attribute__((ext_vector_type(8)));
typedef _Float16 half4 __attribute__((ext_vector_type(4)));
typedef float f32x4 __attribute__((ext_vector_type(4)));
typedef unsigned int u32x4 __attribute__((ext_vector_type(4)));

// split two f32x4 (8 consecutive f32) into fp16 hi + lo residual
__device__ inline void split8(const f32x4 a, const f32x4 b, half8& hi, half8& lo) {
  const float f[8] = {a.x, a.y, a.z, a.w, b.x, b.y, b.z, b.w};
  #pragma unroll
  for (int e = 0; e < 8; ++e) {
    _Float16 h = (_Float16)f[e];
    hi[e] = h;
    lo[e] = (_Float16)(f[e] - (float)h);
  }
}

// -----------------------------------------------------------------------------
// K1 (MFMA): u_hat[i][b][jd] fp16 = sum_k W[i][jd][k] * x[b][i][k]
// u = wh*xh + wh*xl + wl*xh (split-fp16, ~2^-21 rel err).
// A = W (M=jd), B = x (N=b); D: row=(lane>>4)*4+r = jd, col=lane&15 = b.
// TRUE ROUND-6 CONFIG incl. __launch_bounds__(256,3) -> VGPR ~84.
// Rounds 7-12 accidentally carried (256,4) -> VGPR capped at 64, which
// evicts the 16xhalf8 x-fragments + 4-deep W prefetch from registers;
// compiler re-loads x per col-group -> FETCH 850MB, k1 ~480us. (256,3)
// keeps all fragments resident: FETCH ~390MB, k1 ~240us (round 6 measured).
// Other refuted deviations: nt loads +370MB HBM (r8); nt stores +200MB RMW
// (r9); 2-wave blocks thrash L3 (r10); burst-after-prefetch reorder (r11).
// -----------------------------------------------------------------------------
__global__ __launch_bounds__(256, 3) void k1_uhat(
    const float* __restrict__ x, const float* __restrict__ W,
    __half* __restrict__ uhat) {
  __shared__ __half tile[4 * 64 * 64];     // 4 waves x 8KB, wave-private
  const int i = blockIdx.x;                // 0..1151
  const int lane = threadIdx.x & 63;
  const int wave = threadIdx.x >> 6;
  const int kof = (lane >> 4) * 8;         // k sub-offset (frag layout)
  char* my = (char*)(tile + wave * 64 * 64);

  // ---- x fragments (B-operand: col b = m*16 + (lane&15)), split once ----
  half8 xh0[4], xh1[4], xl0[4], xl1[4];
  #pragma unroll
  for (int m = 0; m < 4; ++m) {
    const float* xr = x + ((size_t)(m * 16 + (lane & 15)) * I_DIM + i) * K_DIM + kof;
    split8(*(const f32x4*)xr,        *(const f32x4*)(xr + 4),  xh0[m], xl0[m]);
    split8(*(const f32x4*)(xr + 32), *(const f32x4*)(xr + 36), xh1[m], xl1[m]);
  }

  f32x4 w0[4], w1[4], w2[4], w3[4];
  auto loadW = [&](int cg, f32x4* dst) {
    const int row = wave * 512 + cg * 16 + (lane & 15);     // jd row (A-operand)
    const float* p = W + ((size_t)i * JD + row) * K_DIM + kof;
    dst[0] = *(const f32x4*)p;
    dst[1] = *(const f32x4*)(p + 4);
    dst[2] = *(const f32x4*)(p + 32);
    dst[3] = *(const f32x4*)(p + 36);
  };

  auto process = [&](int cg, const f32x4* wc) {
    half8 wh0, wl0, wh1, wl1;
    split8(wc[0], wc[1], wh0, wl0);
    split8(wc[2], wc[3], wh1, wl1);
    const int g = lane >> 4;
    const int c = (cg & 3) * 4 + g;        // logical 8B chunk (jd_local/4)
    #pragma unroll
    for (int m = 0; m < 4; ++m) {
      f32x4 acc = {0.f, 0.f, 0.f, 0.f};
      acc = __builtin_amdgcn_mfma_f32_16x16x32_f16(wh0, xh0[m], acc, 0, 0, 0);
      acc = __builtin_amdgcn_mfma_f32_16x16x32_f16(wh1, xh1[m], acc, 0, 0, 0);
      acc = __builtin_amdgcn_mfma_f32_16x16x32_f16(wh0, xl0[m], acc, 0, 0, 0);
      acc = __builtin_amdgcn_mfma_f32_16x16x32_f16(wh1, xl1[m], acc, 0, 0, 0);
      acc = __builtin_amdgcn_mfma_f32_16x16x32_f16(wl0, xh0[m], acc, 0, 0, 0);
      acc = __builtin_amdgcn_mfma_f32_16x16x32_f16(wl1, xh1[m], acc, 0, 0, 0);
      const int b = m * 16 + (lane & 15);
      half4 o;
      #pragma unroll
      for (int r = 0; r < 4; ++r) o[r] = (_Float16)acc[r];
      // swizzled ds_write: row b (128B), phys chunk = c ^ ((b&7)<<1)
      *(half4*)(my + b * 128 + ((c ^ ((b & 7) << 1)) * 8)) = o;
    }
    if ((cg & 3) == 3) {
      // burst 8KB tile -> global: 8 instrs x (8 rows x 128B dense)
      const int jd0 = wave * 512 + (cg & ~3) * 16;   // tile's first jd
      #pragma unroll
      for (int t = 0; t < 8; ++t) {
        const int b = t * 8 + (lane >> 3);
        const int c2 = (lane & 7) * 2;               // even chunk -> 16B aligned
        const u32x4 v = *(const u32x4*)(my + b * 128 + ((c2 ^ ((b & 7) << 1)) * 8));
        *(u32x4*)((char*)(uhat + ((size_t)i * B_DIM + b) * JD + jd0) + (lane & 7) * 16) = v;
      }
    }
  };

  loadW(0, w0); loadW(1, w1); loadW(2, w2); loadW(3, w3);
  #pragma unroll 1
  for (int cg = 0; cg < 32; cg += 4) {
    process(cg + 0, w0); if (cg + 4 < 32) loadW(cg + 4, w0);
    process(cg + 1, w1); if (cg + 5 < 32) loadW(cg + 5, w1);
    process(cg + 2, w2); if (cg + 6 < 32) loadW(cg + 6, w2);
    process(cg + 3, w3); if (cg + 7 < 32) loadW(cg + 7, w3);
  }
}

// -----------------------------------------------------------------------------
// K3: s0 = (1/J) * sum_i u_hat -> squash -> v0.  u_hat layout [i][b][jd].
// -----------------------------------------------------------------------------
__global__ __launch_bounds__(256) void k3_s0(
    const __half* __restrict__ uhat, float* __restrict__ v0) {
  const int b = blockIdx.y;
  const int jd = blockIdx.x * 512 + threadIdx.x * 2;
  const __half* p = uhat + (size_t)b * JD + jd;
  float s0 = 0.f, s1 = 0.f;
  #pragma unroll 16
  for (int i = 0; i < I_DIM; ++i) {
    const __half2 h = *(const __half2*)(p + (size_t)i * B_DIM * JD);
    s0 += __low2float(h);
    s1 += __high2float(h);
  }
  s0 *= (1.f / 64.f);
  s1 *= (1.f / 64.f);
  float n2 = s0 * s0 + s1 * s1;
  #pragma unroll
  for (int w = 1; w < 16; w <<= 1) n2 += __shfl_xor(n2, w);
  const float sc = n2 / (1.f + n2) * rsqrtf(n2 + 1e-9f);
  float* o = v0 + (size_t)b * JD + jd;
  o[0] = s0 * sc;
  o[1] = s1 * sc;
}

// -----------------------------------------------------------------------------
// K4: one routing pass. u_hat row for (b,i) = uhat[(i*B + b)*JD], contiguous 4KB.
// -----------------------------------------------------------------------------
__global__ __launch_bounds__(64) void k4_route(
    const __half* __restrict__ uhat, const float* __restrict__ v,
    float* __restrict__ spart) {
  const int chunk = blockIdx.x;   // 0..NCHUNK-1
  const int b = blockIdx.y;       // 0..63
  const int lane = threadIdx.x;   // 0..63
  const int jq = lane >> 2;       // 0..15
  const int d0 = (lane & 3) * 8;

  float vr[4][8];
  #pragma unroll
  for (int q = 0; q < 4; ++q) {
    const float* vp = v + ((size_t)b * J_DIM + q * 16 + jq) * D_DIM + d0;
    f32x4 a0 = *(const f32x4*)vp;
    f32x4 a1 = *(const f32x4*)(vp + 4);
    vr[q][0] = a0.x; vr[q][1] = a0.y; vr[q][2] = a0.z; vr[q][3] = a0.w;
    vr[q][4] = a1.x; vr[q][5] = a1.y; vr[q][6] = a1.z; vr[q][7] = a1.w;
  }
  float sacc[4][8];
  #pragma unroll
  for (int q = 0; q < 4; ++q)
    #pragma unroll
    for (int cc = 0; cc < 8; ++cc) sacc[q][cc] = 0.f;

  for (int ii = 0; ii < ICHUNK; ++ii) {
    const int i = chunk * ICHUNK + ii;
    const __half* row = uhat + ((size_t)i * B_DIM + b) * JD;
    float ur[4][8];
    float a[4];
    #pragma unroll
    for (int q = 0; q < 4; ++q) {
      u32x4 raw = *(const u32x4*)&row[q * 512 + lane * 8];
      const __half* hp = (const __half*)&raw;
      float p = 0.f;
      #pragma unroll
      for (int cc = 0; cc < 8; ++cc) {
        ur[q][cc] = __half2float(hp[cc]);
        p = fmaf(ur[q][cc], vr[q][cc], p);
      }
      p += __shfl_xor(p, 1);
      p += __shfl_xor(p, 2);
      a[q] = p;  // a[b, j=q*16+jq], replicated over the quad
    }
    float m = fmaxf(fmaxf(a[0], a[1]), fmaxf(a[2], a[3]));
    #pragma unroll
    for (int w = 4; w < 64; w <<= 1) m = fmaxf(m, __shfl_xor(m, w));
    float e[4]; float es = 0.f;
    #pragma unroll
    for (int q = 0; q < 4; ++q) { e[q] = __expf(a[q] - m); es += e[q]; }
    #pragma unroll
    for (int w = 4; w < 64; w <<= 1) es += __shfl_xor(es, w);
    const float inv = 4.f / es;  // each j counted 4x in the wave sum
    #pragma unroll
    for (int q = 0; q < 4; ++q) {
      const float cj = e[q] * inv;
      #pragma unroll
      for (int cc = 0; cc < 8; ++cc)
        sacc[q][cc] = fmaf(cj, ur[q][cc], sacc[q][cc]);
    }
  }
  float* sp = spart + ((size_t)(b * NCHUNK + chunk)) * JD;
  #pragma unroll
  for (int q = 0; q < 4; ++q) {
    float* o = sp + (q * 16 + jq) * D_DIM + d0;
    *(f32x4*)o       = f32x4{sacc[q][0], sacc[q][1], sacc[q][2], sacc[q][3]};
    *(f32x4*)(o + 4) = f32x4{sacc[q][4], sacc[q][5], sacc[q][6], sacc[q][7]};
  }
}

// -----------------------------------------------------------------------------
// K5: reduce s-partials over chunks -> squash -> vout (+optional vprev sum).
// -----------------------------------------------------------------------------
__global__ __launch_bounds__(256) void k5_reduce(
    const float* __restrict__ spart, const float* __restrict__ vprev,
    float* __restrict__ vout, float* __restrict__ vsum) {
  const int b = blockIdx.y;
  const int jd = blockIdx.x * 256 + threadIdx.x;
  const float* p = spart + (size_t)b * NCHUNK * JD + jd;
  float s = 0.f;
  #pragma unroll 8
  for (int ch = 0; ch < NCHUNK; ++ch) s += p[(size_t)ch * JD];
  float n2 = s * s;
  #pragma unroll
  for (int w = 1; w < 32; w <<= 1) n2 += __shfl_xor(n2, w);
  const float sc = n2 / (1.f + n2) * rsqrtf(n2 + 1e-9f);
  const float vv = s * sc;
  vout[(size_t)b * JD + jd] = vv;
  if (vsum) vsum[(size_t)b * JD + jd] = vv + vprev[(size_t)b * JD + jd];
}

extern "C" void kernel_launch(void* const* d_in, const int* in_sizes, int n_in,
                              void* d_out, int out_size, void* d_ws, size_t ws_size,
                              hipStream_t stream) {
  const float* x = (const float*)d_in[0];   // (B, I, 1, K, 1) f32
  const float* W = (const float*)d_in[1];   // (1, I, J, D, K) f32
  float* out = (float*)d_out;               // (B, J, 1, D, 1) f32

  char* ws = (char*)d_ws;
  __half* uhat = (__half*)ws;                                   // 302 MB, [i][b][jd]
  size_t off = (size_t)B_DIM * I_DIM * JD * sizeof(__half);
  float* spart = (float*)(ws + off);                            // 37.75 MB
  off += (size_t)B_DIM * NCHUNK * JD * sizeof(float);
  float* v0 = (float*)(ws + off);   off += (size_t)B_DIM * JD * sizeof(float);
  float* v1 = (float*)(ws + off);   off += (size_t)B_DIM * JD * sizeof(float);
  float* vsum = (float*)(ws + off);

  // u_hat via split-fp16 MFMA; LDS-staged dense burst stores (round-6 exact,
  // incl. launch_bounds (256,3))
  k1_uhat<<<I_DIM, 256, 0, stream>>>(x, W, uhat);
  // it 0: s0 = mean_i u_hat -> v0
  k3_s0<<<dim3(4, B_DIM), 256, 0, stream>>>(uhat, v0);
  // it 1: b1 = u.v0 -> softmax -> s1 -> v1 (and vsum = v0+v1)
  k4_route<<<dim3(NCHUNK, B_DIM), 64, 0, stream>>>(uhat, v0, spart);
  k5_reduce<<<dim3(8, B_DIM), 256, 0, stream>>>(spart, v0, v1, vsum);
  // it 2: b2 = u.(v0+v1) -> softmax -> s2 -> v2 = output
  k4_route<<<dim3(NCHUNK, B_DIM), 64, 0, stream>>>(uhat, vsum, spart);
  k5_reduce<<<dim3(8, B_DIM), 256, 0, stream>>>(spart, nullptr, out, nullptr);
}